// Round 1
// baseline (244.090 us; speedup 1.0000x reference)
//
#include <hip/hip_runtime.h>
#include <math.h>

#define B_ 4096
#define L_ 200
#define D_ 256

// ---------------- pooling: one wave per batch row, lane holds 4 dims ----------------
__global__ __launch_bounds__(256) void pool_kernel(
    const int* __restrict__ tokens, const int* __restrict__ lengths,
    const float* __restrict__ emb, float* __restrict__ pooled) {
  const int tid = threadIdx.x;
  const int wv = tid >> 6, lane = tid & 63;
  const int b = blockIdx.x * 4 + wv;
  const int len = lengths[b];
  const int* trow = tokens + b * L_;
  const float4* embv = (const float4*)emb;   // emb row = 64 float4
  float4 a0 = make_float4(0.f, 0.f, 0.f, 0.f);
  float4 a1 = a0, a2 = a0, a3 = a0;
  for (int l0 = 0; l0 < len; l0 += 64) {
    int nt = len - l0; nt = nt > 64 ? 64 : nt;
    int tk = (lane < nt) ? trow[l0 + lane] : 0;   // coalesced token load
    int j = 0;
    for (; j + 4 <= nt; j += 4) {
      int t0 = __shfl(tk, j);
      int t1 = __shfl(tk, j + 1);
      int t2 = __shfl(tk, j + 2);
      int t3 = __shfl(tk, j + 3);
      float4 v0 = embv[(size_t)t0 * 64 + lane];
      float4 v1 = embv[(size_t)t1 * 64 + lane];
      float4 v2 = embv[(size_t)t2 * 64 + lane];
      float4 v3 = embv[(size_t)t3 * 64 + lane];
      a0.x += v0.x; a0.y += v0.y; a0.z += v0.z; a0.w += v0.w;
      a1.x += v1.x; a1.y += v1.y; a1.z += v1.z; a1.w += v1.w;
      a2.x += v2.x; a2.y += v2.y; a2.z += v2.z; a2.w += v2.w;
      a3.x += v3.x; a3.y += v3.y; a3.z += v3.z; a3.w += v3.w;
    }
    for (; j < nt; j++) {
      int t0 = __shfl(tk, j);
      float4 v0 = embv[(size_t)t0 * 64 + lane];
      a0.x += v0.x; a0.y += v0.y; a0.z += v0.z; a0.w += v0.w;
    }
  }
  const float inv = 1.0f / (float)len;
  float4 r;
  r.x = (a0.x + a1.x + a2.x + a3.x) * inv;
  r.y = (a0.y + a1.y + a2.y + a3.y) * inv;
  r.z = (a0.z + a1.z + a2.z + a3.z) * inv;
  r.w = (a0.w + a1.w + a2.w + a3.w) * inv;
  ((float4*)pooled)[(size_t)b * 64 + lane] = r;
}

// ---------------- pack W1 so gemm reads are coalesced ----------------
// W1p[kb*1024 + d*4 + j] = W1[d*256 + kb*4 + j]   (kb in [0,64), j in [0,4))
__global__ __launch_bounds__(256) void w1_pack_kernel(const float* __restrict__ W1,
                                                      float* __restrict__ W1p) {
  int kb = blockIdx.x;       // 0..63
  int d = threadIdx.x;       // 0..255
  float4 v = ((const float4*)W1)[d * 64 + kb];
  ((float4*)W1p)[kb * 256 + d] = v;
}

// ---------------- z = pooled @ W1^T + b1 ; 16 rows/block, wave owns 4 rows ----------------
__global__ __launch_bounds__(256) void gemm_z_kernel(
    const float* __restrict__ pooled, const float* __restrict__ W1p,
    const float* __restrict__ b1, float* __restrict__ z) {
  __shared__ float4 P4[16 * 64];   // 16 rows x 256 k = 16 KB
  const int tid = threadIdx.x;
  const int b0 = blockIdx.x * 16;
  const float4* pooled4 = (const float4*)pooled;
#pragma unroll
  for (int i = 0; i < 4; i++)
    P4[tid + i * 256] = pooled4[(size_t)b0 * 64 + tid + i * 256];
  __syncthreads();
  const int wv = tid >> 6, lane = tid & 63;
  const int r0 = wv * 4;
  float4 bb = ((const float4*)b1)[lane];
  float acc[4][4];
#pragma unroll
  for (int r = 0; r < 4; r++) {
    acc[r][0] = bb.x; acc[r][1] = bb.y; acc[r][2] = bb.z; acc[r][3] = bb.w;
  }
  const float4* w4 = (const float4*)W1p;
  for (int kb = 0; kb < 64; kb++) {
    // lane's 4 output dims: 4 consecutive float4 (64B contiguous per lane, 4KB per wave)
    float4 wk0 = w4[kb * 256 + lane * 4 + 0];
    float4 wk1 = w4[kb * 256 + lane * 4 + 1];
    float4 wk2 = w4[kb * 256 + lane * 4 + 2];
    float4 wk3 = w4[kb * 256 + lane * 4 + 3];
#pragma unroll
    for (int r = 0; r < 4; r++) {
      float4 p = P4[(r0 + r) * 64 + kb];   // wave-uniform -> LDS broadcast
      acc[r][0] += p.x * wk0.x + p.y * wk0.y + p.z * wk0.z + p.w * wk0.w;
      acc[r][1] += p.x * wk1.x + p.y * wk1.y + p.z * wk1.z + p.w * wk1.w;
      acc[r][2] += p.x * wk2.x + p.y * wk2.y + p.z * wk2.z + p.w * wk2.w;
      acc[r][3] += p.x * wk3.x + p.y * wk3.y + p.z * wk3.z + p.w * wk3.w;
    }
  }
  float4* z4 = (float4*)z;
#pragma unroll
  for (int r = 0; r < 4; r++) {
    float4 o = make_float4(acc[r][0], acc[r][1], acc[r][2], acc[r][3]);
    z4[(size_t)(b0 + r0 + r) * 64 + lane] = o;
  }
}

// ---------------- batch stats: column sums, coalesced, 64 atomics/address ----------------
__global__ __launch_bounds__(256) void stats_kernel(const float* __restrict__ z,
                                                    float* __restrict__ ssum,
                                                    float* __restrict__ ssq) {
  const int d = threadIdx.x;
  const int r0 = blockIdx.x * 64;
  float s = 0.f, q = 0.f;
  for (int i = 0; i < 64; i++) {
    float v = z[(size_t)(r0 + i) * 256 + d];
    s += v; q += v * v;
  }
  atomicAdd(&ssum[d], s);
  atomicAdd(&ssq[d], q);
}

// ---------------- BN + ReLU + dot head + per-row BCE; wave per row ----------------
__global__ __launch_bounds__(256) void head_kernel(
    const float* __restrict__ z, const float* __restrict__ ssum,
    const float* __restrict__ ssq, const float* __restrict__ gamma,
    const float* __restrict__ beta, const float* __restrict__ w2,
    const float* __restrict__ b2, const float* __restrict__ t,
    float* __restrict__ out, float* __restrict__ bce) {
  const int tid = threadIdx.x;
  const int wv = tid >> 6, lane = tid & 63;
  const int b = blockIdx.x * 4 + wv;
  float4 s4 = ((const float4*)ssum)[lane];
  float4 q4 = ((const float4*)ssq)[lane];
  float4 g4 = ((const float4*)gamma)[lane];
  float4 be4 = ((const float4*)beta)[lane];
  float4 w24 = ((const float4*)w2)[lane];
  const float invB = 1.0f / 4096.0f;
  float4 A4, C4;
  {
    float m = s4.x * invB, v = q4.x * invB - m * m;
    float rs = rsqrtf(v + 1e-5f); A4.x = g4.x * rs; C4.x = be4.x - m * A4.x;
  }
  {
    float m = s4.y * invB, v = q4.y * invB - m * m;
    float rs = rsqrtf(v + 1e-5f); A4.y = g4.y * rs; C4.y = be4.y - m * A4.y;
  }
  {
    float m = s4.z * invB, v = q4.z * invB - m * m;
    float rs = rsqrtf(v + 1e-5f); A4.z = g4.z * rs; C4.z = be4.z - m * A4.z;
  }
  {
    float m = s4.w * invB, v = q4.w * invB - m * m;
    float rs = rsqrtf(v + 1e-5f); A4.w = g4.w * rs; C4.w = be4.w - m * A4.w;
  }
  float4 zv = ((const float4*)z)[(size_t)b * 64 + lane];
  float h0 = fmaxf(A4.x * zv.x + C4.x, 0.f);
  float h1 = fmaxf(A4.y * zv.y + C4.y, 0.f);
  float h2 = fmaxf(A4.z * zv.z + C4.z, 0.f);
  float h3 = fmaxf(A4.w * zv.w + C4.w, 0.f);
  float part = h0 * w24.x + h1 * w24.y + h2 * w24.z + h3 * w24.w;
#pragma unroll
  for (int off = 32; off > 0; off >>= 1) part += __shfl_down(part, off);
  if (lane == 0) {
    float logit = part + b2[0];
    out[1 + b] = logit;
    float tb = t[b];
    bce[b] = fmaxf(logit, 0.f) - logit * tb + log1pf(expf(-fabsf(logit)));
  }
}

// ---------------- final deterministic loss reduction ----------------
__global__ __launch_bounds__(256) void loss_kernel(const float* __restrict__ bce,
                                                   float* __restrict__ out) {
  __shared__ float red[4];
  const int tid = threadIdx.x;
  float s = 0.f;
  for (int i = 0; i < 16; i++) s += bce[tid + i * 256];
#pragma unroll
  for (int off = 32; off > 0; off >>= 1) s += __shfl_down(s, off);
  if ((tid & 63) == 0) red[tid >> 6] = s;
  __syncthreads();
  if (tid == 0) out[0] = (red[0] + red[1] + red[2] + red[3]) * (1.0f / 4096.0f);
}

extern "C" void kernel_launch(void* const* d_in, const int* in_sizes, int n_in,
                              void* d_out, int out_size, void* d_ws, size_t ws_size,
                              hipStream_t stream) {
  const int* tokens = (const int*)d_in[0];
  const int* lengths = (const int*)d_in[1];
  const float* t = (const float*)d_in[2];
  const float* emb = (const float*)d_in[3];
  const float* W1 = (const float*)d_in[4];
  const float* b1 = (const float*)d_in[5];
  const float* gamma = (const float*)d_in[6];
  const float* beta = (const float*)d_in[7];
  const float* w2 = (const float*)d_in[8];
  const float* b2 = (const float*)d_in[9];
  float* out = (float*)d_out;

  float* wsf = (float*)d_ws;
  float* pooled = wsf;                 // 4096*256          = 1,048,576 floats
  float* z = wsf + 1048576;            // 4096*256          = 1,048,576
  float* W1p = wsf + 2097152;          // 256*256           = 65,536
  float* ssum = wsf + 2162688;         // 256
  float* ssq = wsf + 2162944;          // 256
  float* bce = wsf + 2163200;          // 4096
  // total ~8.3 MiB of d_ws

  hipMemsetAsync(ssum, 0, 512 * sizeof(float), stream);   // ssum + ssq
  w1_pack_kernel<<<64, 256, 0, stream>>>(W1, W1p);
  pool_kernel<<<1024, 256, 0, stream>>>(tokens, lengths, emb, pooled);
  gemm_z_kernel<<<256, 256, 0, stream>>>(pooled, W1p, b1, z);
  stats_kernel<<<64, 256, 0, stream>>>(z, ssum, ssq);
  head_kernel<<<1024, 256, 0, stream>>>(z, ssum, ssq, gamma, beta, w2, b2, t, out, bce);
  loss_kernel<<<1, 256, 0, stream>>>(bce, out);
}

// Round 2
// 240.820 us; speedup vs baseline: 1.0136x; 1.0136x over previous
//
#include <hip/hip_runtime.h>
#include <math.h>

#define L_ 200

// ---------------- pooling: 2 waves per row (halves), + W1 pack piggybacked ----------------
__global__ __launch_bounds__(256) void pool_pack_kernel(
    const int* __restrict__ tokens, const int* __restrict__ lengths,
    const float* __restrict__ emb, float* __restrict__ pooled,
    const float* __restrict__ W1, float* __restrict__ W1p) {
  const int tid = threadIdx.x;
  // blocks 0..63 also transpose-pack W1 (one float4 per thread)
  if (blockIdx.x < 64) {
    float4 v = ((const float4*)W1)[tid * 64 + blockIdx.x];
    ((float4*)W1p)[blockIdx.x * 256 + tid] = v;
  }
  const int wv = tid >> 6, lane = tid & 63;
  const int row = blockIdx.x * 2 + (wv >> 1);
  const int half = wv & 1;
  const int len = lengths[row];
  const int* trow = tokens + row * L_;
  const float4* embv = (const float4*)emb;   // emb row = 64 float4
  float4 a0 = make_float4(0.f, 0.f, 0.f, 0.f);
  float4 a1 = a0, a2 = a0, a3 = a0;
  for (int l0 = half * 64; l0 < len; l0 += 128) {
    int nt = len - l0; nt = nt > 64 ? 64 : nt;
    int tk = (lane < nt) ? trow[l0 + lane] : 0;   // coalesced token load
    int j = 0;
    for (; j + 4 <= nt; j += 4) {
      int t0 = __shfl(tk, j);
      int t1 = __shfl(tk, j + 1);
      int t2 = __shfl(tk, j + 2);
      int t3 = __shfl(tk, j + 3);
      float4 v0 = embv[(size_t)t0 * 64 + lane];
      float4 v1 = embv[(size_t)t1 * 64 + lane];
      float4 v2 = embv[(size_t)t2 * 64 + lane];
      float4 v3 = embv[(size_t)t3 * 64 + lane];
      a0.x += v0.x; a0.y += v0.y; a0.z += v0.z; a0.w += v0.w;
      a1.x += v1.x; a1.y += v1.y; a1.z += v1.z; a1.w += v1.w;
      a2.x += v2.x; a2.y += v2.y; a2.z += v2.z; a2.w += v2.w;
      a3.x += v3.x; a3.y += v3.y; a3.z += v3.z; a3.w += v3.w;
    }
    for (; j < nt; j++) {
      int t0 = __shfl(tk, j);
      float4 v0 = embv[(size_t)t0 * 64 + lane];
      a0.x += v0.x; a0.y += v0.y; a0.z += v0.z; a0.w += v0.w;
    }
  }
  float4 r;
  r.x = a0.x + a1.x + a2.x + a3.x;
  r.y = a0.y + a1.y + a2.y + a3.y;
  r.z = a0.z + a1.z + a2.z + a3.z;
  r.w = a0.w + a1.w + a2.w + a3.w;
  __shared__ float4 part[2][64];
  if (half) part[wv >> 1][lane] = r;
  __syncthreads();
  if (!half) {
    float4 o = part[wv >> 1][lane];
    const float inv = 1.0f / (float)len;
    r.x = (r.x + o.x) * inv;
    r.y = (r.y + o.y) * inv;
    r.z = (r.z + o.z) * inv;
    r.w = (r.w + o.w) * inv;
    ((float4*)pooled)[(size_t)row * 64 + lane] = r;
  }
}

// ---------------- z = pooled @ W1^T + b1, fused per-block BN partial stats ----------------
__global__ __launch_bounds__(256) void gemm_stats_kernel(
    const float* __restrict__ pooled, const float* __restrict__ W1p,
    const float* __restrict__ b1, float* __restrict__ z,
    float* __restrict__ psum, float* __restrict__ psq) {
  __shared__ float4 SH[1024];   // 16 KB: pooled tile during loop, stats after
  const int tid = threadIdx.x;
  const int b0 = blockIdx.x * 16;
  const float4* pooled4 = (const float4*)pooled;
#pragma unroll
  for (int i = 0; i < 4; i++)
    SH[tid + i * 256] = pooled4[(size_t)b0 * 64 + tid + i * 256];
  __syncthreads();
  const int wv = tid >> 6, lane = tid & 63;
  const int r0 = wv * 4;
  float4 bb = ((const float4*)b1)[lane];
  float acc[4][4];
#pragma unroll
  for (int r = 0; r < 4; r++) {
    acc[r][0] = bb.x; acc[r][1] = bb.y; acc[r][2] = bb.z; acc[r][3] = bb.w;
  }
  const float4* w4 = (const float4*)W1p;
  for (int kb = 0; kb < 64; kb++) {
    float4 wk0 = w4[kb * 256 + lane * 4 + 0];
    float4 wk1 = w4[kb * 256 + lane * 4 + 1];
    float4 wk2 = w4[kb * 256 + lane * 4 + 2];
    float4 wk3 = w4[kb * 256 + lane * 4 + 3];
#pragma unroll
    for (int r = 0; r < 4; r++) {
      float4 p = SH[(r0 + r) * 64 + kb];   // wave-uniform -> LDS broadcast
      acc[r][0] += p.x * wk0.x + p.y * wk0.y + p.z * wk0.z + p.w * wk0.w;
      acc[r][1] += p.x * wk1.x + p.y * wk1.y + p.z * wk1.z + p.w * wk1.w;
      acc[r][2] += p.x * wk2.x + p.y * wk2.y + p.z * wk2.z + p.w * wk2.w;
      acc[r][3] += p.x * wk3.x + p.y * wk3.y + p.z * wk3.z + p.w * wk3.w;
    }
  }
  float4* z4 = (float4*)z;
  float4 s = make_float4(0.f, 0.f, 0.f, 0.f), q = s;
#pragma unroll
  for (int r = 0; r < 4; r++) {
    float4 o = make_float4(acc[r][0], acc[r][1], acc[r][2], acc[r][3]);
    z4[(size_t)(b0 + r0 + r) * 64 + lane] = o;
    s.x += o.x; s.y += o.y; s.z += o.z; s.w += o.w;
    q.x += o.x * o.x; q.y += o.y * o.y; q.z += o.z * o.z; q.w += o.w * o.w;
  }
  __syncthreads();   // done reading pooled tile; reuse SH for stats
  SH[wv * 64 + lane] = s;
  SH[256 + wv * 64 + lane] = q;
  __syncthreads();
  if (tid < 64) {
    float4 S = make_float4(0.f, 0.f, 0.f, 0.f), Q = S;
#pragma unroll
    for (int w = 0; w < 4; w++) {
      float4 a = SH[w * 64 + tid];
      float4 b = SH[256 + w * 64 + tid];
      S.x += a.x; S.y += a.y; S.z += a.z; S.w += a.w;
      Q.x += b.x; Q.y += b.y; Q.z += b.z; Q.w += b.w;
    }
    ((float4*)psum)[blockIdx.x * 64 + tid] = S;
    ((float4*)psq)[blockIdx.x * 64 + tid] = Q;
  }
}

// ---------------- finalize BN: A[d] = gamma*rsqrt(var+eps), C[d] = beta - mu*A ----------------
__global__ __launch_bounds__(256) void bn_reduce_kernel(
    const float* __restrict__ psum, const float* __restrict__ psq,
    const float* __restrict__ gamma, const float* __restrict__ beta,
    float* __restrict__ A, float* __restrict__ C) {
  const int t = threadIdx.x;
  const int dd = t & 15, c = t >> 4;
  const int d = blockIdx.x * 16 + dd;
  float s = 0.f, q = 0.f;
#pragma unroll
  for (int i = 0; i < 16; i++) {
    int p = c * 16 + i;
    s += psum[p * 256 + d];
    q += psq[p * 256 + d];
  }
  __shared__ float sl[16][17], ql[16][17];
  sl[c][dd] = s; ql[c][dd] = q;
  __syncthreads();
  if (t < 16) {
    float S = 0.f, Q = 0.f;
#pragma unroll
    for (int c2 = 0; c2 < 16; c2++) { S += sl[c2][t]; Q += ql[c2][t]; }
    int dg = blockIdx.x * 16 + t;
    float m = S * (1.0f / 4096.0f);
    float v = Q * (1.0f / 4096.0f) - m * m;
    float a = gamma[dg] * rsqrtf(v + 1e-5f);
    A[dg] = a;
    C[dg] = beta[dg] - m * a;
  }
}

// ---------------- BN-apply + ReLU + dot head + per-row BCE; wave per row ----------------
__global__ __launch_bounds__(256) void head_kernel(
    const float* __restrict__ z, const float* __restrict__ A,
    const float* __restrict__ C, const float* __restrict__ w2,
    const float* __restrict__ b2, const float* __restrict__ t,
    float* __restrict__ out, float* __restrict__ bce) {
  const int tid = threadIdx.x;
  const int wv = tid >> 6, lane = tid & 63;
  const int b = blockIdx.x * 4 + wv;
  float4 A4 = ((const float4*)A)[lane];
  float4 C4 = ((const float4*)C)[lane];
  float4 w24 = ((const float4*)w2)[lane];
  float4 zv = ((const float4*)z)[(size_t)b * 64 + lane];
  float h0 = fmaxf(A4.x * zv.x + C4.x, 0.f);
  float h1 = fmaxf(A4.y * zv.y + C4.y, 0.f);
  float h2 = fmaxf(A4.z * zv.z + C4.z, 0.f);
  float h3 = fmaxf(A4.w * zv.w + C4.w, 0.f);
  float part = h0 * w24.x + h1 * w24.y + h2 * w24.z + h3 * w24.w;
#pragma unroll
  for (int off = 32; off > 0; off >>= 1) part += __shfl_down(part, off);
  if (lane == 0) {
    float logit = part + b2[0];
    out[1 + b] = logit;
    float tb = t[b];
    bce[b] = fmaxf(logit, 0.f) - logit * tb + log1pf(expf(-fabsf(logit)));
  }
}

// ---------------- final deterministic loss reduction ----------------
__global__ __launch_bounds__(256) void loss_kernel(const float* __restrict__ bce,
                                                   float* __restrict__ out) {
  __shared__ float red[4];
  const int tid = threadIdx.x;
  float s = 0.f;
  for (int i = 0; i < 16; i++) s += bce[tid + i * 256];
#pragma unroll
  for (int off = 32; off > 0; off >>= 1) s += __shfl_down(s, off);
  if ((tid & 63) == 0) red[tid >> 6] = s;
  __syncthreads();
  if (tid == 0) out[0] = (red[0] + red[1] + red[2] + red[3]) * (1.0f / 4096.0f);
}

extern "C" void kernel_launch(void* const* d_in, const int* in_sizes, int n_in,
                              void* d_out, int out_size, void* d_ws, size_t ws_size,
                              hipStream_t stream) {
  const int* tokens = (const int*)d_in[0];
  const int* lengths = (const int*)d_in[1];
  const float* t = (const float*)d_in[2];
  const float* emb = (const float*)d_in[3];
  const float* W1 = (const float*)d_in[4];
  const float* b1 = (const float*)d_in[5];
  const float* gamma = (const float*)d_in[6];
  const float* beta = (const float*)d_in[7];
  const float* w2 = (const float*)d_in[8];
  const float* b2 = (const float*)d_in[9];
  float* out = (float*)d_out;

  float* wsf = (float*)d_ws;
  float* pooled = wsf;                 // 1,048,576 floats
  float* z = wsf + 1048576;            // 1,048,576
  float* W1p = wsf + 2097152;          // 65,536
  float* psum = wsf + 2162688;         // 65,536 (256 blocks x 256 dims)
  float* psq = wsf + 2228224;          // 65,536
  float* A = wsf + 2293760;            // 256
  float* C = wsf + 2294016;            // 256
  float* bce = wsf + 2294272;          // 4,096
  // total ~8.8 MiB of d_ws

  pool_pack_kernel<<<2048, 256, 0, stream>>>(tokens, lengths, emb, pooled, W1, W1p);
  gemm_stats_kernel<<<256, 256, 0, stream>>>(pooled, W1p, b1, z, psum, psq);
  bn_reduce_kernel<<<16, 256, 0, stream>>>(psum, psq, gamma, beta, A, C);
  head_kernel<<<1024, 256, 0, stream>>>(z, A, C, w2, b2, t, out, bce);
  loss_kernel<<<1, 256, 0, stream>>>(bce, out);
}